// Round 9
// baseline (264.071 us; speedup 1.0000x reference)
//
#include <hip/hip_runtime.h>
#include <hip/hip_bf16.h>

#define B_    16
#define CIN_  128
#define COUT_ 256
#define H_    80
#define W_    80
#define HO_   40
#define WO_   40
#define KK_   9
#define SK_   1152      // CIN_*KK_
#define NPIX_ 25600     // B_*HO_*WO_
#define NKS_  36        // K / 32

typedef __attribute__((ext_vector_type(8))) short short8;
typedef __attribute__((ext_vector_type(4))) float floatx4;

__device__ __forceinline__ unsigned short f2bu(float v) {
  __hip_bfloat16 h = __float2bfloat16(v);
  return *reinterpret_cast<unsigned short*>(&h);
}
__device__ __forceinline__ float bu2f(unsigned short u) {
  return __uint_as_float(((unsigned)u) << 16);
}
// async global->LDS DMA, 16B per lane. LDS dest = wave-uniform base + lane*16.
__device__ __forceinline__ void gl_lds16(const unsigned short* g, unsigned short* l) {
  __builtin_amdgcn_global_load_lds(
      (const __attribute__((address_space(1))) unsigned int*)(const void*)g,
      (__attribute__((address_space(3))) unsigned int*)(void*)l, 16, 0, 0);
}

// ------------------------------------------------- KT: pack weights for MFMA
// (verified round 3) K reordered as s' = kk*128 + ci. Apk[ks][m][quad][j] bf16.
__global__ __launch_bounds__(256) void k_pack(const float* __restrict__ dw,
                                              unsigned short* __restrict__ Apk) {
  int t = blockIdx.x * 256 + threadIdx.x;   // 0..294911
  int j  = t & 7;
  int qd = (t >> 3) & 3;
  int m  = (t >> 5) & 255;
  int ks = t >> 13;
  int k  = ks * 32 + qd * 8 + j;
  int kk = k >> 7, ci = k & 127;
  Apk[t] = f2bu(dw[m * SK_ + ci * KK_ + kk]);
}

// --------------------- KC: x -> channels-last bf16 (xcl) + fused offset conv
// Block = (b, y). Stages x[b,:,y,:] (128ci x 80x) in LDS once; writes the
// channels-last bf16 copy, and for even y also computes the 18x40 offset
// dot-products for ho=y/2 (the offset conv reads exactly this row's even-x
// columns) — removes the separate k_offsets kernel and its global re-read.
__global__ __launch_bounds__(256) void k_cl(const float* __restrict__ x,
                                            const float* __restrict__ ow,
                                            const float* __restrict__ ob,
                                            unsigned short* __restrict__ xcl,
                                            float* __restrict__ off) {
  __shared__ float ts[CIN_][W_ + 1];   // 41.5 KB
  __shared__ float owl[18 * CIN_];     //  9.2 KB
  __shared__ float obl[18];
  const int tid = threadIdx.x;
  const int b = blockIdx.x / H_;
  const int y = blockIdx.x % H_;
  const bool even = (y & 1) == 0;

  for (int j = tid; j < CIN_ * 20; j += 256) {
    int ci = j / 20, xq = j % 20;
    float4 v = *(const float4*)&x[(((size_t)b * CIN_ + ci) * H_ + y) * W_ + xq * 4];
    ts[ci][xq * 4 + 0] = v.x;
    ts[ci][xq * 4 + 1] = v.y;
    ts[ci][xq * 4 + 2] = v.z;
    ts[ci][xq * 4 + 3] = v.w;
  }
  if (even) {
    for (int j = tid; j < 18 * CIN_; j += 256) owl[j] = ow[j];
    if (tid < 18) obl[tid] = ob[tid];
  }
  __syncthreads();

  unsigned short* op = xcl + ((size_t)b * H_ * W_ + (size_t)y * W_) * CIN_;
  for (int j = tid; j < W_ * 32; j += 256) {
    int xx = j >> 5, cg = j & 31;
    unsigned short b0 = f2bu(ts[cg * 4 + 0][xx]);
    unsigned short b1 = f2bu(ts[cg * 4 + 1][xx]);
    unsigned short b2 = f2bu(ts[cg * 4 + 2][xx]);
    unsigned short b3 = f2bu(ts[cg * 4 + 3][xx]);
    uint2 pk = make_uint2((unsigned)b0 | ((unsigned)b1 << 16),
                          (unsigned)b2 | ((unsigned)b3 << 16));
    *(uint2*)(op + (size_t)xx * CIN_ + cg * 4) = pk;
  }

  if (even) {
    const int ho = y >> 1;
    for (int i = tid; i < 18 * WO_; i += 256) {
      int o = i / WO_, wo = i - o * WO_;
      float acc = obl[o];
      const float* wr = &owl[o * CIN_];
#pragma unroll 4
      for (int ci = 0; ci < CIN_; ci++) acc += wr[ci] * ts[ci][2 * wo];
      off[((b * 18 + o) * HO_ + ho) * WO_ + wo] = acc;
    }
  }
}

// ------------------------------------------ K2a: sampling from channels-last
// (verified round 6) XCD-swizzled by b; coalesced 16B corner loads.
__global__ __launch_bounds__(256) void k_sample_cl(const unsigned short* __restrict__ xcl,
                                                   const float* __restrict__ off,
                                                   unsigned short* __restrict__ Spk) {
  __shared__ __align__(16) int   pidx[80 * 4];
  __shared__ __align__(16) float pw[80 * 4];
  const int tid = threadIdx.x;
  const int j0   = blockIdx.x;         // 0..2879
  const int xcd  = j0 & 7;
  const int s    = j0 >> 3;
  const int b_hi = s / 180;
  const int t0   = s % 180;
  const int g    = t0 / 9;
  const int kk   = t0 % 9;
  const int b    = b_hi * 8 + xcd;
  const int ho0  = g * 2;

  if (tid < 80) {
    int hop = tid / 40, px = tid % 40;
    int ho = ho0 + hop;
    float dy = off[((b * 18 + 2 * kk) * HO_ + ho) * WO_ + px];
    float dx = off[((b * 18 + 2 * kk + 1) * HO_ + ho) * WO_ + px];
    float py  = (float)(2 * ho - 1 + (kk / 3)) + dy;
    float pxf = (float)(2 * px - 1 + (kk % 3)) + dx;
    float y0f = floorf(py), x0f = floorf(pxf);
    float wy1 = py - y0f, wx1 = pxf - x0f;
    float wy0 = 1.f - wy1, wx0 = 1.f - wx1;
    int y0 = (int)y0f, x0 = (int)x0f;
    int y1 = y0 + 1, x1 = x0 + 1;
    bool vy0 = (y0 >= 0) && (y0 < H_);
    bool vy1 = (y1 >= 0) && (y1 < H_);
    bool vx0 = (x0 >= 0) && (x0 < W_);
    bool vx1 = (x1 >= 0) && (x1 < W_);
    int y0c = min(max(y0, 0), H_ - 1), y1c = min(max(y1, 0), H_ - 1);
    int x0c = min(max(x0, 0), W_ - 1), x1c = min(max(x1, 0), W_ - 1);
    pidx[tid * 4 + 0] = (y0c * W_ + x0c) << 7;  pw[tid * 4 + 0] = (vy0 && vx0) ? wy0 * wx0 : 0.f;
    pidx[tid * 4 + 1] = (y0c * W_ + x1c) << 7;  pw[tid * 4 + 1] = (vy0 && vx1) ? wy0 * wx1 : 0.f;
    pidx[tid * 4 + 2] = (y1c * W_ + x0c) << 7;  pw[tid * 4 + 2] = (vy1 && vx0) ? wy1 * wx0 : 0.f;
    pidx[tid * 4 + 3] = (y1c * W_ + x1c) << 7;  pw[tid * 4 + 3] = (vy1 && vx1) ? wy1 * wx1 : 0.f;
  }
  __syncthreads();

  const unsigned short* xb = xcl + (size_t)b * (H_ * W_ * CIN_);
#pragma unroll
  for (int it = 0; it < 5; it++) {
    int i = it * 256 + tid;            // (pxh, oct), oct fastest
    int oct = i & 15;
    int pxh = i >> 4;                  // 0..79
    int4   I  = *(const int4*)&pidx[pxh * 4];
    float4 Wv = *(const float4*)&pw[pxh * 4];
    short8 c00 = *(const short8*)(xb + I.x + oct * 8);
    short8 c01 = *(const short8*)(xb + I.y + oct * 8);
    short8 c10 = *(const short8*)(xb + I.z + oct * 8);
    short8 c11 = *(const short8*)(xb + I.w + oct * 8);
    short8 r;
#pragma unroll
    for (int i2 = 0; i2 < 8; i2++) {
      float v = Wv.x * bu2f((unsigned short)c00[i2]) +
                Wv.y * bu2f((unsigned short)c01[i2]) +
                Wv.z * bu2f((unsigned short)c10[i2]) +
                Wv.w * bu2f((unsigned short)c11[i2]);
      r[i2] = (short)f2bu(v);
    }
    int p  = b * 1600 + (ho0 + (pxh / 40)) * 40 + (pxh % 40);
    int pt = p >> 4, lm = p & 15;
    int ks = kk * 4 + (oct >> 2);
    int qd = oct & 3;
    *(short8*)&Spk[(((size_t)pt * NKS_ + ks) * 64 + qd * 16 + lm) * 8] = r;
  }
}

// -------- K2b: MFMA GEMM, LDS double-buffer, K split x2, XCD-affine swizzle
// Block = 128 couts x 64 px x half-K (18 steps), 4 waves. blockIdx arranged
// so bid&7 == b&7: this block runs on the XCD whose L2 holds the Spk tiles
// k_sample_cl wrote for batch image b (writer used the same swizzle).
// Partial C accumulated into zeroed d_out via fp32 atomics (bias dropped:
// per-channel bias cancels exactly through BN).
__global__ __launch_bounds__(256) void k_gemm(const unsigned short* __restrict__ Apk,
                                              const unsigned short* __restrict__ Spk,
                                              float* __restrict__ outp) {
  __shared__ __align__(16) unsigned short a_sh[2][4096];  // 16 KB
  __shared__ __align__(16) unsigned short b_sh[2][2048];  //  8 KB

  const int tid = threadIdx.x;
  const int wv = tid >> 6;
  const int ln = tid & 63;
  const int lm = ln & 15;
  const int qd = ln >> 4;
  const int wm = wv >> 1;              // cout-half within block's 128
  const int wn = wv & 1;               // px-half (2 pt tiles)

  // XCD-affine decomposition: 1600 = 8 xcd * (2 b) * (25 g4) * (2 chalf*2 ks)
  const int bid  = blockIdx.x;
  const int xcd  = bid & 7;
  const int i    = bid >> 3;           // 0..199
  const int b    = xcd + 8 * (i / 100);
  const int r_   = i % 100;
  const int g4l  = r_ >> 2;            // 0..24
  const int chalf  = (r_ >> 1) & 1;
  const int ksplit = r_ & 1;
  const int pt0 = (b * 25 + g4l) * 4;
  const int ks0 = ksplit * 18;

  const unsigned short* agbase = Apk + (size_t)ks0 * 8192 + chalf * 4096 + tid * 8;
  const unsigned short* bgbase = Spk + ((size_t)(pt0 + wv) * NKS_ + ks0) * 512 + ln * 8;

  floatx4 acc[4][2];
#pragma unroll
  for (int mt = 0; mt < 4; mt++)
#pragma unroll
    for (int nt = 0; nt < 2; nt++) acc[mt][nt] = (floatx4){0.f, 0.f, 0.f, 0.f};

  // prologue: stage local ks=0 into buf 0
  gl_lds16(agbase,        &a_sh[0][0] + wv * 512);
  gl_lds16(agbase + 2048, &a_sh[0][2048] + wv * 512);
  gl_lds16(bgbase,        &b_sh[0][0] + wv * 512);
  __syncthreads();

  for (int ks = 0; ks < 18; ks++) {
    const int buf = ks & 1, nb = buf ^ 1;
    if (ks + 1 < 18) {
      gl_lds16(agbase + (size_t)(ks + 1) * 8192,        &a_sh[nb][0] + wv * 512);
      gl_lds16(agbase + (size_t)(ks + 1) * 8192 + 2048, &a_sh[nb][2048] + wv * 512);
      gl_lds16(bgbase + (size_t)(ks + 1) * 512,         &b_sh[nb][0] + wv * 512);
    }
    const unsigned short* al = &a_sh[buf][0] + (wm * 64 + lm) * 32 + qd * 8;
    const unsigned short* bl = &b_sh[buf][0] + wn * 1024 + ln * 8;
    short8 a0 = *(const short8*)(al + 0 * 512);
    short8 a1 = *(const short8*)(al + 1 * 512);
    short8 a2 = *(const short8*)(al + 2 * 512);
    short8 a3 = *(const short8*)(al + 3 * 512);
    short8 b0 = *(const short8*)(bl);
    short8 b1 = *(const short8*)(bl + 512);
    acc[0][0] = __builtin_amdgcn_mfma_f32_16x16x32_bf16(a0, b0, acc[0][0], 0, 0, 0);
    acc[0][1] = __builtin_amdgcn_mfma_f32_16x16x32_bf16(a0, b1, acc[0][1], 0, 0, 0);
    acc[1][0] = __builtin_amdgcn_mfma_f32_16x16x32_bf16(a1, b0, acc[1][0], 0, 0, 0);
    acc[1][1] = __builtin_amdgcn_mfma_f32_16x16x32_bf16(a1, b1, acc[1][1], 0, 0, 0);
    acc[2][0] = __builtin_amdgcn_mfma_f32_16x16x32_bf16(a2, b0, acc[2][0], 0, 0, 0);
    acc[2][1] = __builtin_amdgcn_mfma_f32_16x16x32_bf16(a2, b1, acc[2][1], 0, 0, 0);
    acc[3][0] = __builtin_amdgcn_mfma_f32_16x16x32_bf16(a3, b0, acc[3][0], 0, 0, 0);
    acc[3][1] = __builtin_amdgcn_mfma_f32_16x16x32_bf16(a3, b1, acc[3][1], 0, 0, 0);
    __syncthreads();
  }

  // Epilogue: atomic partial-C accumulate (layout verified r3-r8).
#pragma unroll
  for (int nt = 0; nt < 2; nt++) {
    int p = (pt0 + wn * 2 + nt) * 16 + lm;
    int bb = p / 1600, rem = p % 1600;
    float* ob = outp + (size_t)bb * COUT_ * 1600 + rem;
#pragma unroll
    for (int mt = 0; mt < 4; mt++) {
#pragma unroll
      for (int r = 0; r < 4; r++) {
        const int c = chalf * 128 + wm * 64 + mt * 16 + qd * 4 + r;
        atomicAdd(&ob[(size_t)c * 1600], acc[mt][nt][r]);
      }
    }
  }
}

// ----------------------------------------------- K2c: per-channel sum/sq-sum
// (verified round 5) One block per cout channel; no atomics.
__global__ __launch_bounds__(256) void k_stats(const float* __restrict__ io,
                                               float* __restrict__ accum) {
  const int c = blockIdx.x;
  const int tid = threadIdx.x;
  float s1 = 0.f, s2 = 0.f;
  for (int i = tid; i < NPIX_; i += 256) {
    int b = i / 1600, r = i - b * 1600;
    float v = io[((size_t)b * COUT_ + c) * 1600 + r];
    s1 += v;
    s2 += v * v;
  }
#pragma unroll
  for (int d = 1; d < 64; d <<= 1) {
    s1 += __shfl_xor(s1, d, 64);
    s2 += __shfl_xor(s2, d, 64);
  }
  __shared__ float rs[4], rq[4];
  if ((tid & 63) == 0) { rs[tid >> 6] = s1; rq[tid >> 6] = s2; }
  __syncthreads();
  if (tid == 0) {
    accum[c]         = rs[0] + rs[1] + rs[2] + rs[3];
    accum[COUT_ + c] = rq[0] + rq[1] + rq[2] + rq[3];
  }
}

// --------------------------------------------------- K3: BN + SiLU, in place
__global__ __launch_bounds__(256) void k_bn(float* __restrict__ io,
                                            const float* __restrict__ accum,
                                            const float* __restrict__ gamma,
                                            const float* __restrict__ beta) {
  const int t = blockIdx.x * 256 + threadIdx.x;
  const int i0 = t * 4;
  const int c = (i0 / (HO_ * WO_)) % COUT_;
  const float mean = accum[c] * (1.f / NPIX_);
  const float var  = accum[COUT_ + c] * (1.f / NPIX_) - mean * mean;
  const float inv  = rsqrtf(var + 1e-5f);
  const float g  = gamma[c] * inv;
  const float be = beta[c] - mean * g;
  float4 r = *(const float4*)(io + i0);
  float v[4] = {r.x, r.y, r.z, r.w};
#pragma unroll
  for (int q = 0; q < 4; q++) {
    float u = v[q] * g + be;
    v[q] = u / (1.f + expf(-u));
  }
  *(float4*)(io + i0) = make_float4(v[0], v[1], v[2], v[3]);
}

// ----------------------------------------------------------------- launcher
extern "C" void kernel_launch(void* const* d_in, const int* in_sizes, int n_in,
                              void* d_out, int out_size, void* d_ws, size_t ws_size,
                              hipStream_t stream) {
  const float* x     = (const float*)d_in[0];
  const float* ow    = (const float*)d_in[1];
  const float* ob    = (const float*)d_in[2];
  const float* dw    = (const float*)d_in[3];
  const float* gamma = (const float*)d_in[5];
  const float* beta  = (const float*)d_in[6];
  float* out = (float*)d_out;

  float* off   = (float*)d_ws;                                 // 460800 f
  float* accum = off + B_ * 18 * HO_ * WO_;                    // 512 f
  unsigned short* Apk = (unsigned short*)(accum + 2 * COUT_);  // 294912 us
  unsigned short* Spk = Apk + (size_t)SK_ * COUT_;             // 29491200 us
  unsigned short* xcl = Spk + (size_t)NPIX_ * SK_;             // 13107200 us

  hipMemsetAsync(out, 0, (size_t)NPIX_ * COUT_ * sizeof(float), stream);
  k_pack<<<SK_, 256, 0, stream>>>(dw, Apk);
  k_cl<<<B_ * H_, 256, 0, stream>>>(x, ow, ob, xcl, off);
  k_sample_cl<<<B_ * KK_ * 20, 256, 0, stream>>>(xcl, off, Spk);
  k_gemm<<<1600, 256, 0, stream>>>(Apk, Spk, out);
  k_stats<<<COUT_, 256, 0, stream>>>(out, accum);
  k_bn<<<(NPIX_ * COUT_ / 4 + 255) / 256, 256, 0, stream>>>(
      out, accum, gamma, beta);
}

// Round 10
// 231.561 us; speedup vs baseline: 1.1404x; 1.1404x over previous
//
#include <hip/hip_runtime.h>
#include <hip/hip_bf16.h>

#define B_    16
#define CIN_  128
#define COUT_ 256
#define H_    80
#define W_    80
#define HO_   40
#define WO_   40
#define KK_   9
#define SK_   1152      // CIN_*KK_
#define NPIX_ 25600     // B_*HO_*WO_
#define NKS_  36        // K / 32

typedef __attribute__((ext_vector_type(8))) short short8;
typedef __attribute__((ext_vector_type(4))) float floatx4;

__device__ __forceinline__ unsigned short f2bu(float v) {
  __hip_bfloat16 h = __float2bfloat16(v);
  return *reinterpret_cast<unsigned short*>(&h);
}
__device__ __forceinline__ float bu2f(unsigned short u) {
  return __uint_as_float(((unsigned)u) << 16);
}
// async global->LDS DMA, 16B per lane. LDS dest = wave-uniform base + lane*16.
__device__ __forceinline__ void gl_lds16(const unsigned short* g, unsigned short* l) {
  __builtin_amdgcn_global_load_lds(
      (const __attribute__((address_space(1))) unsigned int*)(const void*)g,
      (__attribute__((address_space(3))) unsigned int*)(void*)l, 16, 0, 0);
}

// ------------------------------------------------- KT: pack weights for MFMA
// (verified round 3) K reordered as s' = kk*128 + ci. Apk[ks][m][quad][j] bf16.
__global__ __launch_bounds__(256) void k_pack(const float* __restrict__ dw,
                                              unsigned short* __restrict__ Apk) {
  int t = blockIdx.x * 256 + threadIdx.x;   // 0..294911
  int j  = t & 7;
  int qd = (t >> 3) & 3;
  int m  = (t >> 5) & 255;
  int ks = t >> 13;
  int k  = ks * 32 + qd * 8 + j;
  int kk = k >> 7, ci = k & 127;
  Apk[t] = f2bu(dw[m * SK_ + ci * KK_ + kk]);
}

// --------------------- KC: x -> channels-last bf16 (xcl) + fused offset conv
// (verified round 9)
__global__ __launch_bounds__(256) void k_cl(const float* __restrict__ x,
                                            const float* __restrict__ ow,
                                            const float* __restrict__ ob,
                                            unsigned short* __restrict__ xcl,
                                            float* __restrict__ off) {
  __shared__ float ts[CIN_][W_ + 1];   // 41.5 KB
  __shared__ float owl[18 * CIN_];     //  9.2 KB
  __shared__ float obl[18];
  const int tid = threadIdx.x;
  const int b = blockIdx.x / H_;
  const int y = blockIdx.x % H_;
  const bool even = (y & 1) == 0;

  for (int j = tid; j < CIN_ * 20; j += 256) {
    int ci = j / 20, xq = j % 20;
    float4 v = *(const float4*)&x[(((size_t)b * CIN_ + ci) * H_ + y) * W_ + xq * 4];
    ts[ci][xq * 4 + 0] = v.x;
    ts[ci][xq * 4 + 1] = v.y;
    ts[ci][xq * 4 + 2] = v.z;
    ts[ci][xq * 4 + 3] = v.w;
  }
  if (even) {
    for (int j = tid; j < 18 * CIN_; j += 256) owl[j] = ow[j];
    if (tid < 18) obl[tid] = ob[tid];
  }
  __syncthreads();

  unsigned short* op = xcl + ((size_t)b * H_ * W_ + (size_t)y * W_) * CIN_;
  for (int j = tid; j < W_ * 32; j += 256) {
    int xx = j >> 5, cg = j & 31;
    unsigned short b0 = f2bu(ts[cg * 4 + 0][xx]);
    unsigned short b1 = f2bu(ts[cg * 4 + 1][xx]);
    unsigned short b2 = f2bu(ts[cg * 4 + 2][xx]);
    unsigned short b3 = f2bu(ts[cg * 4 + 3][xx]);
    uint2 pk = make_uint2((unsigned)b0 | ((unsigned)b1 << 16),
                          (unsigned)b2 | ((unsigned)b3 << 16));
    *(uint2*)(op + (size_t)xx * CIN_ + cg * 4) = pk;
  }

  if (even) {
    const int ho = y >> 1;
    for (int i = tid; i < 18 * WO_; i += 256) {
      int o = i / WO_, wo = i - o * WO_;
      float acc = obl[o];
      const float* wr = &owl[o * CIN_];
#pragma unroll 4
      for (int ci = 0; ci < CIN_; ci++) acc += wr[ci] * ts[ci][2 * wo];
      off[((b * 18 + o) * HO_ + ho) * WO_ + wo] = acc;
    }
  }
}

// ------------------------------------------ K2a: sampling from channels-last
// (verified round 6) XCD-swizzled by b; coalesced 16B corner loads.
__global__ __launch_bounds__(256) void k_sample_cl(const unsigned short* __restrict__ xcl,
                                                   const float* __restrict__ off,
                                                   unsigned short* __restrict__ Spk) {
  __shared__ __align__(16) int   pidx[80 * 4];
  __shared__ __align__(16) float pw[80 * 4];
  const int tid = threadIdx.x;
  const int j0   = blockIdx.x;         // 0..2879
  const int xcd  = j0 & 7;
  const int s    = j0 >> 3;
  const int b_hi = s / 180;
  const int t0   = s % 180;
  const int g    = t0 / 9;
  const int kk   = t0 % 9;
  const int b    = b_hi * 8 + xcd;
  const int ho0  = g * 2;

  if (tid < 80) {
    int hop = tid / 40, px = tid % 40;
    int ho = ho0 + hop;
    float dy = off[((b * 18 + 2 * kk) * HO_ + ho) * WO_ + px];
    float dx = off[((b * 18 + 2 * kk + 1) * HO_ + ho) * WO_ + px];
    float py  = (float)(2 * ho - 1 + (kk / 3)) + dy;
    float pxf = (float)(2 * px - 1 + (kk % 3)) + dx;
    float y0f = floorf(py), x0f = floorf(pxf);
    float wy1 = py - y0f, wx1 = pxf - x0f;
    float wy0 = 1.f - wy1, wx0 = 1.f - wx1;
    int y0 = (int)y0f, x0 = (int)x0f;
    int y1 = y0 + 1, x1 = x0 + 1;
    bool vy0 = (y0 >= 0) && (y0 < H_);
    bool vy1 = (y1 >= 0) && (y1 < H_);
    bool vx0 = (x0 >= 0) && (x0 < W_);
    bool vx1 = (x1 >= 0) && (x1 < W_);
    int y0c = min(max(y0, 0), H_ - 1), y1c = min(max(y1, 0), H_ - 1);
    int x0c = min(max(x0, 0), W_ - 1), x1c = min(max(x1, 0), W_ - 1);
    pidx[tid * 4 + 0] = (y0c * W_ + x0c) << 7;  pw[tid * 4 + 0] = (vy0 && vx0) ? wy0 * wx0 : 0.f;
    pidx[tid * 4 + 1] = (y0c * W_ + x1c) << 7;  pw[tid * 4 + 1] = (vy0 && vx1) ? wy0 * wx1 : 0.f;
    pidx[tid * 4 + 2] = (y1c * W_ + x0c) << 7;  pw[tid * 4 + 2] = (vy1 && vx0) ? wy1 * wx0 : 0.f;
    pidx[tid * 4 + 3] = (y1c * W_ + x1c) << 7;  pw[tid * 4 + 3] = (vy1 && vx1) ? wy1 * wx1 : 0.f;
  }
  __syncthreads();

  const unsigned short* xb = xcl + (size_t)b * (H_ * W_ * CIN_);
#pragma unroll
  for (int it = 0; it < 5; it++) {
    int i = it * 256 + tid;            // (pxh, oct), oct fastest
    int oct = i & 15;
    int pxh = i >> 4;                  // 0..79
    int4   I  = *(const int4*)&pidx[pxh * 4];
    float4 Wv = *(const float4*)&pw[pxh * 4];
    short8 c00 = *(const short8*)(xb + I.x + oct * 8);
    short8 c01 = *(const short8*)(xb + I.y + oct * 8);
    short8 c10 = *(const short8*)(xb + I.z + oct * 8);
    short8 c11 = *(const short8*)(xb + I.w + oct * 8);
    short8 r;
#pragma unroll
    for (int i2 = 0; i2 < 8; i2++) {
      float v = Wv.x * bu2f((unsigned short)c00[i2]) +
                Wv.y * bu2f((unsigned short)c01[i2]) +
                Wv.z * bu2f((unsigned short)c10[i2]) +
                Wv.w * bu2f((unsigned short)c11[i2]);
      r[i2] = (short)f2bu(v);
    }
    int p  = b * 1600 + (ho0 + (pxh / 40)) * 40 + (pxh % 40);
    int pt = p >> 4, lm = p & 15;
    int ks = kk * 4 + (oct >> 2);
    int qd = oct & 3;
    *(short8*)&Spk[(((size_t)pt * NKS_ + ks) * 64 + qd * 16 + lm) * 8] = r;
  }
}

// --- K2b: MFMA GEMM. Block = 64 couts x 64 px x half-K, 4 waves, 16 KB LDS.
// 8 blocks/CU resident (32 waves = 100% slots) — max independent barrier
// groups to cover the per-step vmcnt drain. A staged once per step (4 KB,
// shared by all 4 waves); B per-wave 1 KB. K split x2: plain stores of
// partial C into C0/C1 (no memset, no atomic RMW). XCD-affine: bid&7 == b&7
// so Spk reads hit the writer XCD's L2. Bias dropped (cancels through BN).
__global__ __launch_bounds__(256) void k_gemm(const unsigned short* __restrict__ Apk,
                                              const unsigned short* __restrict__ Spk,
                                              float* __restrict__ c0,
                                              float* __restrict__ c1) {
  __shared__ __align__(16) unsigned short a_sh[2][2048];  // 8 KB: 64 couts x 32k
  __shared__ __align__(16) unsigned short b_sh[2][2048];  // 8 KB: 4 waves x 1 tile

  const int tid = threadIdx.x;
  const int wv = tid >> 6;
  const int ln = tid & 63;
  const int lm = ln & 15;
  const int qd = ln >> 4;

  // XCD-affine decomposition: 3200 = 8 xcd * 2 b_hi * 25 pxg * 4 cq * 2 ksp
  const int bid = blockIdx.x;
  const int xcd = bid & 7;
  const int i   = bid >> 3;            // 0..399
  const int b   = xcd + 8 * (i / 200);
  const int r_  = i % 200;
  const int pxg = r_ >> 3;             // 0..24 (64-px group within image)
  const int cq  = (r_ >> 1) & 3;       // cout quarter
  const int ksp = r_ & 1;              // K half
  const int pt0 = b * 100 + pxg * 4;   // 16-px tile base (wave wv takes pt0+wv)
  const int cbase = cq * 64;
  const int ks0 = ksp * 18;

  const unsigned short* agbase = Apk + (size_t)ks0 * 8192 + cbase * 32 + tid * 8;
  const unsigned short* bgbase = Spk + ((size_t)(pt0 + wv) * NKS_ + ks0) * 512 + ln * 8;

  floatx4 acc[4];
#pragma unroll
  for (int mt = 0; mt < 4; mt++) acc[mt] = (floatx4){0.f, 0.f, 0.f, 0.f};

  // prologue: stage local ks=0 into buf 0 (A: one 4KB call; B: 1KB per wave)
  gl_lds16(agbase, &a_sh[0][0] + wv * 512);
  gl_lds16(bgbase, &b_sh[0][0] + wv * 512);
  __syncthreads();

  for (int ks = 0; ks < 18; ks++) {
    const int buf = ks & 1, nb = buf ^ 1;
    if (ks + 1 < 18) {
      gl_lds16(agbase + (size_t)(ks + 1) * 8192, &a_sh[nb][0] + wv * 512);
      gl_lds16(bgbase + (size_t)(ks + 1) * 512,  &b_sh[nb][0] + wv * 512);
    }
    const unsigned short* al = &a_sh[buf][0] + lm * 32 + qd * 8;
    const unsigned short* bl = &b_sh[buf][0] + wv * 512 + ln * 8;
    short8 a0 = *(const short8*)(al + 0 * 512);
    short8 a1 = *(const short8*)(al + 1 * 512);
    short8 a2 = *(const short8*)(al + 2 * 512);
    short8 a3 = *(const short8*)(al + 3 * 512);
    short8 bv = *(const short8*)(bl);
    acc[0] = __builtin_amdgcn_mfma_f32_16x16x32_bf16(a0, bv, acc[0], 0, 0, 0);
    acc[1] = __builtin_amdgcn_mfma_f32_16x16x32_bf16(a1, bv, acc[1], 0, 0, 0);
    acc[2] = __builtin_amdgcn_mfma_f32_16x16x32_bf16(a2, bv, acc[2], 0, 0, 0);
    acc[3] = __builtin_amdgcn_mfma_f32_16x16x32_bf16(a3, bv, acc[3], 0, 0, 0);
    __syncthreads();
  }

  // Epilogue: plain partial-C store (C/D layout verified r3-r9).
  const int p = (pt0 + wv) * 16 + lm;
  const int bb = p / 1600, rem = p % 1600;
  float* ob = (ksp ? c1 : c0) + (size_t)bb * COUT_ * 1600 + rem;
#pragma unroll
  for (int mt = 0; mt < 4; mt++) {
#pragma unroll
    for (int r = 0; r < 4; r++) {
      const int c = cbase + mt * 16 + qd * 4 + r;
      ob[(size_t)c * 1600] = acc[mt][r];
    }
  }
}

// ------------------------------- K2c: per-channel sum/sq-sum over C0+C1
__global__ __launch_bounds__(256) void k_stats(const float* __restrict__ io0,
                                               const float* __restrict__ io1,
                                               float* __restrict__ accum) {
  const int c = blockIdx.x;
  const int tid = threadIdx.x;
  float s1 = 0.f, s2 = 0.f;
  for (int i = tid; i < NPIX_; i += 256) {
    int b = i / 1600, r = i - b * 1600;
    size_t idx = ((size_t)b * COUT_ + c) * 1600 + r;
    float v = io0[idx] + io1[idx];
    s1 += v;
    s2 += v * v;
  }
#pragma unroll
  for (int d = 1; d < 64; d <<= 1) {
    s1 += __shfl_xor(s1, d, 64);
    s2 += __shfl_xor(s2, d, 64);
  }
  __shared__ float rs[4], rq[4];
  if ((tid & 63) == 0) { rs[tid >> 6] = s1; rq[tid >> 6] = s2; }
  __syncthreads();
  if (tid == 0) {
    accum[c]         = rs[0] + rs[1] + rs[2] + rs[3];
    accum[COUT_ + c] = rq[0] + rq[1] + rq[2] + rq[3];
  }
}

// --------------------------- K3: BN + SiLU; reads C0+C1, writes final to C0
__global__ __launch_bounds__(256) void k_bn(float* __restrict__ io0,
                                            const float* __restrict__ io1,
                                            const float* __restrict__ accum,
                                            const float* __restrict__ gamma,
                                            const float* __restrict__ beta) {
  const int t = blockIdx.x * 256 + threadIdx.x;
  const int i0 = t * 4;
  const int c = (i0 / (HO_ * WO_)) % COUT_;
  const float mean = accum[c] * (1.f / NPIX_);
  const float var  = accum[COUT_ + c] * (1.f / NPIX_) - mean * mean;
  const float inv  = rsqrtf(var + 1e-5f);
  const float g  = gamma[c] * inv;
  const float be = beta[c] - mean * g;
  float4 r0 = *(const float4*)(io0 + i0);
  float4 r1 = *(const float4*)(io1 + i0);
  float v[4] = {r0.x + r1.x, r0.y + r1.y, r0.z + r1.z, r0.w + r1.w};
#pragma unroll
  for (int q = 0; q < 4; q++) {
    float u = v[q] * g + be;
    v[q] = u / (1.f + expf(-u));
  }
  *(float4*)(io0 + i0) = make_float4(v[0], v[1], v[2], v[3]);
}

// ----------------------------------------------------------------- launcher
extern "C" void kernel_launch(void* const* d_in, const int* in_sizes, int n_in,
                              void* d_out, int out_size, void* d_ws, size_t ws_size,
                              hipStream_t stream) {
  const float* x     = (const float*)d_in[0];
  const float* ow    = (const float*)d_in[1];
  const float* ob    = (const float*)d_in[2];
  const float* dw    = (const float*)d_in[3];
  const float* gamma = (const float*)d_in[5];
  const float* beta  = (const float*)d_in[6];
  float* out = (float*)d_out;

  float* off   = (float*)d_ws;                                 // 460800 f
  float* accum = off + B_ * 18 * HO_ * WO_;                    // 512 f
  unsigned short* Apk = (unsigned short*)(accum + 2 * COUT_);  // 294912 us
  unsigned short* Spk = Apk + (size_t)SK_ * COUT_;             // 29491200 us
  unsigned short* xcl = Spk + (size_t)NPIX_ * SK_;             // 13107200 us
  // C1 aliases xcl: xcl is dead after k_sample_cl; 13107200 us == 6553600 f.
  float* c1 = (float*)xcl;

  k_pack<<<SK_, 256, 0, stream>>>(dw, Apk);
  k_cl<<<B_ * H_, 256, 0, stream>>>(x, ow, ob, xcl, off);
  k_sample_cl<<<B_ * KK_ * 20, 256, 0, stream>>>(xcl, off, Spk);
  k_gemm<<<3200, 256, 0, stream>>>(Apk, Spk, out, c1);
  k_stats<<<COUT_, 256, 0, stream>>>(out, c1, accum);
  k_bn<<<(NPIX_ * COUT_ / 4 + 255) / 256, 256, 0, stream>>>(
      out, c1, accum, gamma, beta);
}

// Round 11
// 195.469 us; speedup vs baseline: 1.3510x; 1.1846x over previous
//
#include <hip/hip_runtime.h>
#include <hip/hip_bf16.h>

#define B_    16
#define CIN_  128
#define COUT_ 256
#define H_    80
#define W_    80
#define HO_   40
#define WO_   40
#define KK_   9
#define SK_   1152      // CIN_*KK_
#define NPIX_ 25600     // B_*HO_*WO_
#define NKS_  36        // K / 32

typedef __attribute__((ext_vector_type(8))) short short8;
typedef __attribute__((ext_vector_type(4))) float floatx4;

__device__ __forceinline__ unsigned short f2bu(float v) {
  __hip_bfloat16 h = __float2bfloat16(v);
  return *reinterpret_cast<unsigned short*>(&h);
}
__device__ __forceinline__ float bu2f(unsigned short u) {
  return __uint_as_float(((unsigned)u) << 16);
}
__device__ __forceinline__ unsigned int pk2(float a, float b) {
  return (unsigned)f2bu(a) | ((unsigned)f2bu(b) << 16);
}
// async global->LDS DMA, 16B per lane. LDS dest = wave-uniform base + lane*16.
__device__ __forceinline__ void gl_lds16(const unsigned short* g, unsigned short* l) {
  __builtin_amdgcn_global_load_lds(
      (const __attribute__((address_space(1))) unsigned int*)(const void*)g,
      (__attribute__((address_space(3))) unsigned int*)(void*)l, 16, 0, 0);
}

// ------------------------------------------------- KT: pack weights for MFMA
// (verified round 3) K reordered as s' = kk*128 + ci. Apk[ks][m][quad][j] bf16.
__global__ __launch_bounds__(256) void k_pack(const float* __restrict__ dw,
                                              unsigned short* __restrict__ Apk) {
  int t = blockIdx.x * 256 + threadIdx.x;   // 0..294911
  int j  = t & 7;
  int qd = (t >> 3) & 3;
  int m  = (t >> 5) & 255;
  int ks = t >> 13;
  int k  = ks * 32 + qd * 8 + j;
  int kk = k >> 7, ci = k & 127;
  Apk[t] = f2bu(dw[m * SK_ + ci * KK_ + kk]);
}

// --------------- KC v2: x -> channels-last bf16 + fused offset conv
// Block = (b, y), XCD-affine (b = (bid>>3)/80*8 + bid&7) so xcl and off land
// in the L2 of the XCD that k_sample_cl/k_gemm (same affinity) will read.
// LDS tile is PACKED bf16 pairs, row stride 41 words: phase-1 writes are
// lane-stride-2 (2-way = free), phase-2 reads 4-way on 4 instrs only.
// 30 KB LDS -> 5 blocks/CU (was 50 KB / 3 blocks, 5M conflict cycles).
__global__ __launch_bounds__(256) void k_cl(const float* __restrict__ x,
                                            const float* __restrict__ ow,
                                            const float* __restrict__ ob,
                                            unsigned short* __restrict__ xcl,
                                            float* __restrict__ off) {
  __shared__ unsigned int ts[CIN_ * 41];   // 21 KB: word xw holds x=2xw (lo), 2xw+1 (hi)
  __shared__ float owl[18 * CIN_];         // 9.2 KB
  __shared__ float obl[18];
  const int tid = threadIdx.x;
  const int bid = blockIdx.x;              // 0..1279
  const int xcd = bid & 7;
  const int i0_ = bid >> 3;                // 0..159
  const int b   = (i0_ / 80) * 8 + xcd;
  const int y   = i0_ % 80;
  const bool even = (y & 1) == 0;

  // phase 1: coalesced float4 read along x, packed bf16 write into LDS
  for (int j = tid; j < CIN_ * 20; j += 256) {
    int ci = j / 20, xq = j % 20;
    float4 v = *(const float4*)&x[(((size_t)b * CIN_ + ci) * H_ + y) * W_ + xq * 4];
    ts[ci * 41 + xq * 2 + 0] = pk2(v.x, v.y);
    ts[ci * 41 + xq * 2 + 1] = pk2(v.z, v.w);
  }
  if (even) {
    for (int j = tid; j < 18 * CIN_; j += 256) owl[j] = ow[j];
    if (tid < 18) obl[tid] = ob[tid];
  }
  __syncthreads();

  // phase 2: transpose out of LDS; global stores 256B-contiguous per 32 lanes
  unsigned short* op = xcl + ((size_t)b * H_ * W_ + (size_t)y * W_) * CIN_;
  for (int j = tid; j < 40 * 32; j += 256) {
    int xw = j >> 5, cg = j & 31;          // xw = x-pair, cg = 4-channel group
    unsigned w0 = ts[(cg * 4 + 0) * 41 + xw];
    unsigned w1 = ts[(cg * 4 + 1) * 41 + xw];
    unsigned w2 = ts[(cg * 4 + 2) * 41 + xw];
    unsigned w3 = ts[(cg * 4 + 3) * 41 + xw];
    uint2 lo = make_uint2((w0 & 0xFFFFu) | (w1 << 16),
                          (w2 & 0xFFFFu) | (w3 << 16));
    uint2 hi = make_uint2((w0 >> 16) | (w1 & 0xFFFF0000u),
                          (w2 >> 16) | (w3 & 0xFFFF0000u));
    *(uint2*)(op + (size_t)(2 * xw) * CIN_ + cg * 4)     = lo;
    *(uint2*)(op + (size_t)(2 * xw + 1) * CIN_ + cg * 4) = hi;
  }

  // fused offset conv (even y): x at even positions = low half of word wo
  if (even) {
    const int ho = y >> 1;
    for (int i = tid; i < 18 * WO_; i += 256) {
      int o = i / WO_, wo = i - o * WO_;
      float acc = obl[o];
      const float* wr = &owl[o * CIN_];
#pragma unroll 4
      for (int ci = 0; ci < CIN_; ci++)
        acc += wr[ci] * bu2f((unsigned short)(ts[ci * 41 + wo] & 0xFFFFu));
      off[((b * 18 + o) * HO_ + ho) * WO_ + wo] = acc;
    }
  }
}

// ------------------------------------------ K2a: sampling from channels-last
// (verified round 6) XCD-swizzled by b; coalesced 16B corner loads.
__global__ __launch_bounds__(256) void k_sample_cl(const unsigned short* __restrict__ xcl,
                                                   const float* __restrict__ off,
                                                   unsigned short* __restrict__ Spk) {
  __shared__ __align__(16) int   pidx[80 * 4];
  __shared__ __align__(16) float pw[80 * 4];
  const int tid = threadIdx.x;
  const int j0   = blockIdx.x;         // 0..2879
  const int xcd  = j0 & 7;
  const int s    = j0 >> 3;
  const int b_hi = s / 180;
  const int t0   = s % 180;
  const int g    = t0 / 9;
  const int kk   = t0 % 9;
  const int b    = b_hi * 8 + xcd;
  const int ho0  = g * 2;

  if (tid < 80) {
    int hop = tid / 40, px = tid % 40;
    int ho = ho0 + hop;
    float dy = off[((b * 18 + 2 * kk) * HO_ + ho) * WO_ + px];
    float dx = off[((b * 18 + 2 * kk + 1) * HO_ + ho) * WO_ + px];
    float py  = (float)(2 * ho - 1 + (kk / 3)) + dy;
    float pxf = (float)(2 * px - 1 + (kk % 3)) + dx;
    float y0f = floorf(py), x0f = floorf(pxf);
    float wy1 = py - y0f, wx1 = pxf - x0f;
    float wy0 = 1.f - wy1, wx0 = 1.f - wx1;
    int y0 = (int)y0f, x0 = (int)x0f;
    int y1 = y0 + 1, x1 = x0 + 1;
    bool vy0 = (y0 >= 0) && (y0 < H_);
    bool vy1 = (y1 >= 0) && (y1 < H_);
    bool vx0 = (x0 >= 0) && (x0 < W_);
    bool vx1 = (x1 >= 0) && (x1 < W_);
    int y0c = min(max(y0, 0), H_ - 1), y1c = min(max(y1, 0), H_ - 1);
    int x0c = min(max(x0, 0), W_ - 1), x1c = min(max(x1, 0), W_ - 1);
    pidx[tid * 4 + 0] = (y0c * W_ + x0c) << 7;  pw[tid * 4 + 0] = (vy0 && vx0) ? wy0 * wx0 : 0.f;
    pidx[tid * 4 + 1] = (y0c * W_ + x1c) << 7;  pw[tid * 4 + 1] = (vy0 && vx1) ? wy0 * wx1 : 0.f;
    pidx[tid * 4 + 2] = (y1c * W_ + x0c) << 7;  pw[tid * 4 + 2] = (vy1 && vx0) ? wy1 * wx0 : 0.f;
    pidx[tid * 4 + 3] = (y1c * W_ + x1c) << 7;  pw[tid * 4 + 3] = (vy1 && vx1) ? wy1 * wx1 : 0.f;
  }
  __syncthreads();

  const unsigned short* xb = xcl + (size_t)b * (H_ * W_ * CIN_);
#pragma unroll
  for (int it = 0; it < 5; it++) {
    int i = it * 256 + tid;            // (pxh, oct), oct fastest
    int oct = i & 15;
    int pxh = i >> 4;                  // 0..79
    int4   I  = *(const int4*)&pidx[pxh * 4];
    float4 Wv = *(const float4*)&pw[pxh * 4];
    short8 c00 = *(const short8*)(xb + I.x + oct * 8);
    short8 c01 = *(const short8*)(xb + I.y + oct * 8);
    short8 c10 = *(const short8*)(xb + I.z + oct * 8);
    short8 c11 = *(const short8*)(xb + I.w + oct * 8);
    short8 r;
#pragma unroll
    for (int i2 = 0; i2 < 8; i2++) {
      float v = Wv.x * bu2f((unsigned short)c00[i2]) +
                Wv.y * bu2f((unsigned short)c01[i2]) +
                Wv.z * bu2f((unsigned short)c10[i2]) +
                Wv.w * bu2f((unsigned short)c11[i2]);
      r[i2] = (short)f2bu(v);
    }
    int p  = b * 1600 + (ho0 + (pxh / 40)) * 40 + (pxh % 40);
    int pt = p >> 4, lm = p & 15;
    int ks = kk * 4 + (oct >> 2);
    int qd = oct & 3;
    *(short8*)&Spk[(((size_t)pt * NKS_ + ks) * 64 + qd * 16 + lm) * 8] = r;
  }
}

// --- K2b: MFMA GEMM (verified round 10). 64c x 64px x half-K, 16 KB LDS,
// 8 blocks/CU, plain partial-C stores, XCD-affine.
__global__ __launch_bounds__(256) void k_gemm(const unsigned short* __restrict__ Apk,
                                              const unsigned short* __restrict__ Spk,
                                              float* __restrict__ c0,
                                              float* __restrict__ c1) {
  __shared__ __align__(16) unsigned short a_sh[2][2048];  // 8 KB
  __shared__ __align__(16) unsigned short b_sh[2][2048];  // 8 KB

  const int tid = threadIdx.x;
  const int wv = tid >> 6;
  const int ln = tid & 63;
  const int lm = ln & 15;
  const int qd = ln >> 4;

  const int bid = blockIdx.x;
  const int xcd = bid & 7;
  const int i   = bid >> 3;            // 0..399
  const int b   = xcd + 8 * (i / 200);
  const int r_  = i % 200;
  const int pxg = r_ >> 3;             // 0..24
  const int cq  = (r_ >> 1) & 3;
  const int ksp = r_ & 1;
  const int pt0 = b * 100 + pxg * 4;
  const int cbase = cq * 64;
  const int ks0 = ksp * 18;

  const unsigned short* agbase = Apk + (size_t)ks0 * 8192 + cbase * 32 + tid * 8;
  const unsigned short* bgbase = Spk + ((size_t)(pt0 + wv) * NKS_ + ks0) * 512 + ln * 8;

  floatx4 acc[4];
#pragma unroll
  for (int mt = 0; mt < 4; mt++) acc[mt] = (floatx4){0.f, 0.f, 0.f, 0.f};

  gl_lds16(agbase, &a_sh[0][0] + wv * 512);
  gl_lds16(bgbase, &b_sh[0][0] + wv * 512);
  __syncthreads();

  for (int ks = 0; ks < 18; ks++) {
    const int buf = ks & 1, nb = buf ^ 1;
    if (ks + 1 < 18) {
      gl_lds16(agbase + (size_t)(ks + 1) * 8192, &a_sh[nb][0] + wv * 512);
      gl_lds16(bgbase + (size_t)(ks + 1) * 512,  &b_sh[nb][0] + wv * 512);
    }
    const unsigned short* al = &a_sh[buf][0] + lm * 32 + qd * 8;
    const unsigned short* bl = &b_sh[buf][0] + wv * 512 + ln * 8;
    short8 a0 = *(const short8*)(al + 0 * 512);
    short8 a1 = *(const short8*)(al + 1 * 512);
    short8 a2 = *(const short8*)(al + 2 * 512);
    short8 a3 = *(const short8*)(al + 3 * 512);
    short8 bv = *(const short8*)(bl);
    acc[0] = __builtin_amdgcn_mfma_f32_16x16x32_bf16(a0, bv, acc[0], 0, 0, 0);
    acc[1] = __builtin_amdgcn_mfma_f32_16x16x32_bf16(a1, bv, acc[1], 0, 0, 0);
    acc[2] = __builtin_amdgcn_mfma_f32_16x16x32_bf16(a2, bv, acc[2], 0, 0, 0);
    acc[3] = __builtin_amdgcn_mfma_f32_16x16x32_bf16(a3, bv, acc[3], 0, 0, 0);
    __syncthreads();
  }

  const int p = (pt0 + wv) * 16 + lm;
  const int bb = p / 1600, rem = p % 1600;
  float* ob = (ksp ? c1 : c0) + (size_t)bb * COUT_ * 1600 + rem;
#pragma unroll
  for (int mt = 0; mt < 4; mt++) {
#pragma unroll
    for (int r = 0; r < 4; r++) {
      const int c = cbase + mt * 16 + qd * 4 + r;
      ob[(size_t)c * 1600] = acc[mt][r];
    }
  }
}

// ------------------- K2c: per-channel sum/sq-sum over C0+C1, 4 blocks/channel
__global__ __launch_bounds__(256) void k_stats(const float* __restrict__ io0,
                                               const float* __restrict__ io1,
                                               float* __restrict__ accum) {
  const int c = blockIdx.x >> 2;
  const int q = blockIdx.x & 3;
  const int tid = threadIdx.x;
  float s1 = 0.f, s2 = 0.f;
  for (int i = q * (NPIX_ / 4) + tid; i < (q + 1) * (NPIX_ / 4); i += 256) {
    int b = i / 1600, r = i - b * 1600;
    size_t idx = ((size_t)b * COUT_ + c) * 1600 + r;
    float v = io0[idx] + io1[idx];
    s1 += v;
    s2 += v * v;
  }
#pragma unroll
  for (int d = 1; d < 64; d <<= 1) {
    s1 += __shfl_xor(s1, d, 64);
    s2 += __shfl_xor(s2, d, 64);
  }
  __shared__ float rs[4], rq[4];
  if ((tid & 63) == 0) { rs[tid >> 6] = s1; rq[tid >> 6] = s2; }
  __syncthreads();
  if (tid == 0) {
    atomicAdd(&accum[c],         rs[0] + rs[1] + rs[2] + rs[3]);
    atomicAdd(&accum[COUT_ + c], rq[0] + rq[1] + rq[2] + rq[3]);
  }
}

// --------------------------- K3: BN + SiLU; reads C0+C1, writes final to C0
__global__ __launch_bounds__(256) void k_bn(float* __restrict__ io0,
                                            const float* __restrict__ io1,
                                            const float* __restrict__ accum,
                                            const float* __restrict__ gamma,
                                            const float* __restrict__ beta) {
  const int t = blockIdx.x * 256 + threadIdx.x;
  const int i0 = t * 4;
  const int c = (i0 / (HO_ * WO_)) % COUT_;
  const float mean = accum[c] * (1.f / NPIX_);
  const float var  = accum[COUT_ + c] * (1.f / NPIX_) - mean * mean;
  const float inv  = rsqrtf(var + 1e-5f);
  const float g  = gamma[c] * inv;
  const float be = beta[c] - mean * g;
  float4 r0 = *(const float4*)(io0 + i0);
  float4 r1 = *(const float4*)(io1 + i0);
  float v[4] = {r0.x + r1.x, r0.y + r1.y, r0.z + r1.z, r0.w + r1.w};
#pragma unroll
  for (int q = 0; q < 4; q++) {
    float u = v[q] * g + be;
    v[q] = u / (1.f + expf(-u));
  }
  *(float4*)(io0 + i0) = make_float4(v[0], v[1], v[2], v[3]);
}

// ----------------------------------------------------------------- launcher
extern "C" void kernel_launch(void* const* d_in, const int* in_sizes, int n_in,
                              void* d_out, int out_size, void* d_ws, size_t ws_size,
                              hipStream_t stream) {
  const float* x     = (const float*)d_in[0];
  const float* ow    = (const float*)d_in[1];
  const float* ob    = (const float*)d_in[2];
  const float* dw    = (const float*)d_in[3];
  const float* gamma = (const float*)d_in[5];
  const float* beta  = (const float*)d_in[6];
  float* out = (float*)d_out;

  float* off   = (float*)d_ws;                                 // 460800 f
  float* accum = off + B_ * 18 * HO_ * WO_;                    // 512 f
  unsigned short* Apk = (unsigned short*)(accum + 2 * COUT_);  // 294912 us
  unsigned short* Spk = Apk + (size_t)SK_ * COUT_;             // 29491200 us
  unsigned short* xcl = Spk + (size_t)NPIX_ * SK_;             // 13107200 us
  // C1 aliases xcl: xcl is dead after k_sample_cl; 13107200 us == 6553600 f.
  float* c1 = (float*)xcl;

  hipMemsetAsync(accum, 0, 2 * COUT_ * sizeof(float), stream);
  k_pack<<<SK_, 256, 0, stream>>>(dw, Apk);
  k_cl<<<B_ * H_, 256, 0, stream>>>(x, ow, ob, xcl, off);
  k_sample_cl<<<B_ * KK_ * 20, 256, 0, stream>>>(xcl, off, Spk);
  k_gemm<<<3200, 256, 0, stream>>>(Apk, Spk, out, c1);
  k_stats<<<COUT_ * 4, 256, 0, stream>>>(out, c1, accum);
  k_bn<<<(NPIX_ * COUT_ / 4 + 255) / 256, 256, 0, stream>>>(
      out, c1, accum, gamma, beta);
}